// Round 1
// baseline (181.799 us; speedup 1.0000x reference)
//
#include <hip/hip_runtime.h>
#include <hip/hip_bf16.h>

typedef __attribute__((ext_vector_type(8))) short short8;
typedef __attribute__((ext_vector_type(4))) float f32x4;

#define HD 64
#define NH 12
#define SEQ 2048
#define BATCH 2
#define CDIM 768

static __device__ __forceinline__ unsigned short f2bf(float f) {
    __hip_bfloat16 h = __float2bfloat16(f);
    return __builtin_bit_cast(unsigned short, h);
}

// ---------------- convert x (f32 -> bf16) ----------------
__global__ void convert_x_kernel(const float* __restrict__ in, unsigned short* __restrict__ out, int n4) {
    int i = blockIdx.x * blockDim.x + threadIdx.x;
    const int stride = gridDim.x * blockDim.x;
    for (; i < n4; i += stride) {
        const float4 v = reinterpret_cast<const float4*>(in)[i];
        ushort4 o;
        o.x = f2bf(v.x); o.y = f2bf(v.y); o.z = f2bf(v.z); o.w = f2bf(v.w);
        reinterpret_cast<ushort4*>(out)[i] = o;
    }
}

// ---------------- transpose + convert (f32 [K][C] -> bf16 [C][K]) ----------------
__global__ __launch_bounds__(256) void transpose_conv_kernel(const float* __restrict__ in,
        unsigned short* __restrict__ out, int K, int C) {
    __shared__ float t[32][33];
    const int k0 = blockIdx.x * 32, c0 = blockIdx.y * 32;
    const int r = threadIdx.x >> 3, c4 = (threadIdx.x & 7) * 4;
    const float4 v = *reinterpret_cast<const float4*>(in + (size_t)(k0 + r) * C + c0 + c4);
    t[r][c4 + 0] = v.x; t[r][c4 + 1] = v.y; t[r][c4 + 2] = v.z; t[r][c4 + 3] = v.w;
    __syncthreads();
    ushort4 o;
    o.x = f2bf(t[c4 + 0][r]); o.y = f2bf(t[c4 + 1][r]);
    o.z = f2bf(t[c4 + 2][r]); o.w = f2bf(t[c4 + 3][r]);
    *reinterpret_cast<ushort4*>(out + (size_t)(c0 + r) * K + k0 + c4) = o;
}

// ---------------- MFMA GEMM: C[M,N] = A[M,K] @ Bt[N,K]^T ----------------
// EPI==0: scatter bf16 into Q/K/V planes [B*NH][SEQ][HD]   (N must be 2304)
// EPI==1: fp32 out += bias                                  (N must be 768)
template<int EPI>
__global__ __launch_bounds__(256, 2) void gemm_kernel(
    const unsigned short* __restrict__ A,
    const unsigned short* __restrict__ Bt,
    const int K, const int N,
    unsigned short* __restrict__ Qo, unsigned short* __restrict__ Ko, unsigned short* __restrict__ Vo,
    float* __restrict__ Cout, const float* __restrict__ bias)
{
    const int tid = threadIdx.x;
    const int wave = tid >> 6, lane = tid & 63;
    const int g = lane >> 4, li = lane & 15;
    const int wr = wave >> 1, wc = wave & 1;
    const int m0 = blockIdx.x * 128, n0 = blockIdx.y * 128;

    __shared__ short As[128 * 40];
    __shared__ short Bs[128 * 40];

    f32x4 acc[4][4];
    #pragma unroll
    for (int i = 0; i < 4; i++)
        #pragma unroll
        for (int j = 0; j < 4; j++)
            acc[i][j] = (f32x4){0.f, 0.f, 0.f, 0.f};

    const int sr = tid >> 1, sc = (tid & 1) * 16;
    const unsigned short* aSrc = A + (size_t)(m0 + sr) * K + sc;
    const unsigned short* bSrc = Bt + (size_t)(n0 + sr) * K + sc;
    short* aDst = As + sr * 40 + sc;
    short* bDst = Bs + sr * 40 + sc;

    for (int k0 = 0; k0 < K; k0 += 32) {
        __syncthreads();
        *reinterpret_cast<short8*>(aDst)     = *reinterpret_cast<const short8*>(aSrc + k0);
        *reinterpret_cast<short8*>(aDst + 8) = *reinterpret_cast<const short8*>(aSrc + k0 + 8);
        *reinterpret_cast<short8*>(bDst)     = *reinterpret_cast<const short8*>(bSrc + k0);
        *reinterpret_cast<short8*>(bDst + 8) = *reinterpret_cast<const short8*>(bSrc + k0 + 8);
        __syncthreads();
        short8 af[4], bfr[4];
        #pragma unroll
        for (int mf = 0; mf < 4; mf++)
            af[mf] = *reinterpret_cast<const short8*>(As + (wr * 64 + mf * 16 + li) * 40 + 8 * g);
        #pragma unroll
        for (int nf = 0; nf < 4; nf++)
            bfr[nf] = *reinterpret_cast<const short8*>(Bs + (wc * 64 + nf * 16 + li) * 40 + 8 * g);
        #pragma unroll
        for (int mf = 0; mf < 4; mf++)
            #pragma unroll
            for (int nf = 0; nf < 4; nf++)
                acc[mf][nf] = __builtin_amdgcn_mfma_f32_16x16x32_bf16(af[mf], bfr[nf], acc[mf][nf], 0, 0, 0);
    }

    #pragma unroll
    for (int mf = 0; mf < 4; mf++) {
        #pragma unroll
        for (int nf = 0; nf < 4; nf++) {
            #pragma unroll
            for (int j = 0; j < 4; j++) {
                const int r = m0 + wr * 64 + mf * 16 + 4 * g + j;
                const int c = n0 + wc * 64 + nf * 16 + li;
                const float v = acc[mf][nf][j];
                if (EPI == 0) {
                    const int s = c / 768, rem = c % 768;
                    const int h = rem >> 6, d = rem & 63;
                    const int b = r >> 11, n = r & (SEQ - 1);
                    unsigned short* dst = (s == 0) ? Qo : (s == 1) ? Ko : Vo;
                    dst[(((size_t)b * NH + h) * SEQ + n) * HD + d] = f2bf(v);
                } else {
                    Cout[(size_t)r * N + c] = v + bias[c];
                }
            }
        }
    }
}

// ---------------- flash attention ----------------
// Q,K,V: bf16 [B*NH][SEQ][HD]; O: bf16 [B][SEQ][CDIM] (col = h*64+d)
__global__ __launch_bounds__(256, 2) void attn_kernel(
    const unsigned short* __restrict__ Q,
    const unsigned short* __restrict__ Kg,
    const unsigned short* __restrict__ Vg,
    unsigned short* __restrict__ O)
{
    const int tid = threadIdx.x;
    const int wave = tid >> 6, lane = tid & 63;
    const int g = lane >> 4, li = lane & 15;
    const int head = blockIdx.y;
    const int b = head / NH, h = head % NH;
    const int q0 = blockIdx.x * 64 + wave * 16;
    const size_t plane = (size_t)head * SEQ * HD;

    __shared__ short Ks[64 * 72];
    __shared__ short Vt[64 * 72];
    __shared__ short Pl[4][16 * 72];

    short8 qf[2];
    {
        const unsigned short* qp = Q + plane + (size_t)(q0 + li) * HD + 8 * g;
        qf[0] = *reinterpret_cast<const short8*>(qp);
        qf[1] = *reinterpret_cast<const short8*>(qp + 32);
    }
    float m_run[4], l_run[4];
    f32x4 o_acc[4];
    #pragma unroll
    for (int j = 0; j < 4; j++) { m_run[j] = -1e30f; l_run[j] = 0.f; }
    #pragma unroll
    for (int nf = 0; nf < 4; nf++) o_acc[nf] = (f32x4){0.f, 0.f, 0.f, 0.f};

    const int sr = tid >> 2, sc = (tid & 3) * 16;

    for (int kv0 = 0; kv0 < SEQ; kv0 += 64) {
        __syncthreads();
        {
            const unsigned short* ksrc = Kg + plane + (size_t)(kv0 + sr) * HD + sc;
            *reinterpret_cast<short8*>(&Ks[sr * 72 + sc])     = *reinterpret_cast<const short8*>(ksrc);
            *reinterpret_cast<short8*>(&Ks[sr * 72 + sc + 8]) = *reinterpret_cast<const short8*>(ksrc + 8);
            const unsigned short* vsrc = Vg + plane + (size_t)(kv0 + sr) * HD + sc;
            short8 v0 = *reinterpret_cast<const short8*>(vsrc);
            short8 v1 = *reinterpret_cast<const short8*>(vsrc + 8);
            #pragma unroll
            for (int i = 0; i < 8; i++) {
                Vt[(sc + i) * 72 + sr]     = v0[i];
                Vt[(sc + 8 + i) * 72 + sr] = v1[i];
            }
        }
        __syncthreads();

        f32x4 s_acc[4];
        #pragma unroll
        for (int nf = 0; nf < 4; nf++) s_acc[nf] = (f32x4){0.f, 0.f, 0.f, 0.f};
        #pragma unroll
        for (int nf = 0; nf < 4; nf++) {
            short8 k0f = *reinterpret_cast<const short8*>(&Ks[(nf * 16 + li) * 72 + 8 * g]);
            short8 k1f = *reinterpret_cast<const short8*>(&Ks[(nf * 16 + li) * 72 + 8 * g + 32]);
            s_acc[nf] = __builtin_amdgcn_mfma_f32_16x16x32_bf16(qf[0], k0f, s_acc[nf], 0, 0, 0);
            s_acc[nf] = __builtin_amdgcn_mfma_f32_16x16x32_bf16(qf[1], k1f, s_acc[nf], 0, 0, 0);
        }

        float p[4][4];
        #pragma unroll
        for (int j = 0; j < 4; j++) {
            const float s0 = s_acc[0][j] * 0.125f, s1 = s_acc[1][j] * 0.125f,
                        s2 = s_acc[2][j] * 0.125f, s3 = s_acc[3][j] * 0.125f;
            float t = fmaxf(fmaxf(s0, s1), fmaxf(s2, s3));
            t = fmaxf(t, __shfl_xor(t, 1));
            t = fmaxf(t, __shfl_xor(t, 2));
            t = fmaxf(t, __shfl_xor(t, 4));
            t = fmaxf(t, __shfl_xor(t, 8));
            const float mnew = fmaxf(m_run[j], t);
            const float corr = __expf(m_run[j] - mnew);
            m_run[j] = mnew;
            const float p0 = __expf(s0 - mnew), p1 = __expf(s1 - mnew),
                        p2 = __expf(s2 - mnew), p3 = __expf(s3 - mnew);
            p[0][j] = p0; p[1][j] = p1; p[2][j] = p2; p[3][j] = p3;
            float sum = p0 + p1 + p2 + p3;
            sum += __shfl_xor(sum, 1);
            sum += __shfl_xor(sum, 2);
            sum += __shfl_xor(sum, 4);
            sum += __shfl_xor(sum, 8);
            l_run[j] = l_run[j] * corr + sum;
            #pragma unroll
            for (int nf = 0; nf < 4; nf++) o_acc[nf][j] *= corr;
        }

        #pragma unroll
        for (int nf = 0; nf < 4; nf++)
            #pragma unroll
            for (int j = 0; j < 4; j++)
                Pl[wave][(4 * g + j) * 72 + nf * 16 + li] = (short)f2bf(p[nf][j]);

        const short8 pa0 = *reinterpret_cast<const short8*>(&Pl[wave][li * 72 + 8 * g]);
        const short8 pa1 = *reinterpret_cast<const short8*>(&Pl[wave][li * 72 + 8 * g + 32]);
        #pragma unroll
        for (int nf = 0; nf < 4; nf++) {
            short8 vb0 = *reinterpret_cast<const short8*>(&Vt[(nf * 16 + li) * 72 + 8 * g]);
            short8 vb1 = *reinterpret_cast<const short8*>(&Vt[(nf * 16 + li) * 72 + 8 * g + 32]);
            o_acc[nf] = __builtin_amdgcn_mfma_f32_16x16x32_bf16(pa0, vb0, o_acc[nf], 0, 0, 0);
            o_acc[nf] = __builtin_amdgcn_mfma_f32_16x16x32_bf16(pa1, vb1, o_acc[nf], 0, 0, 0);
        }
    }

    #pragma unroll
    for (int j = 0; j < 4; j++) {
        const float inv = 1.0f / l_run[j];
        const int n = q0 + 4 * g + j;
        unsigned short* dst = O + ((size_t)b * SEQ + n) * CDIM + h * HD;
        #pragma unroll
        for (int nf = 0; nf < 4; nf++)
            dst[nf * 16 + li] = f2bf(o_acc[nf][j] * inv);
    }
}

extern "C" void kernel_launch(void* const* d_in, const int* in_sizes, int n_in,
                              void* d_out, int out_size, void* d_ws, size_t ws_size,
                              hipStream_t stream) {
    const float* x      = (const float*)d_in[0];
    const float* w_qkv  = (const float*)d_in[1];
    const float* w_proj = (const float*)d_in[2];
    const float* b_proj = (const float*)d_in[3];
    float* out = (float*)d_out;

    char* p = (char*)d_ws;
    auto take = [&](size_t bytes) { char* r = p; p += (bytes + 255) & ~(size_t)255; return r; };
    unsigned short* xb      = (unsigned short*)take((size_t)4096 * 768 * 2);
    unsigned short* wqkv_t  = (unsigned short*)take((size_t)2304 * 768 * 2);
    unsigned short* wproj_t = (unsigned short*)take((size_t)768 * 768 * 2);
    unsigned short* Qb      = (unsigned short*)take((size_t)24 * 2048 * 64 * 2);
    unsigned short* Kb      = (unsigned short*)take((size_t)24 * 2048 * 64 * 2);
    unsigned short* Vb      = (unsigned short*)take((size_t)24 * 2048 * 64 * 2);
    unsigned short* Ob      = (unsigned short*)take((size_t)4096 * 768 * 2);

    convert_x_kernel<<<1024, 256, 0, stream>>>(x, xb, 4096 * 768 / 4);
    transpose_conv_kernel<<<dim3(24, 72), 256, 0, stream>>>(w_qkv, wqkv_t, 768, 2304);
    transpose_conv_kernel<<<dim3(24, 24), 256, 0, stream>>>(w_proj, wproj_t, 768, 768);
    gemm_kernel<0><<<dim3(32, 18), 256, 0, stream>>>(xb, wqkv_t, 768, 2304, Qb, Kb, Vb, nullptr, nullptr);
    attn_kernel<<<dim3(32, 24), 256, 0, stream>>>(Qb, Kb, Vb, Ob);
    gemm_kernel<1><<<dim3(32, 6), 256, 0, stream>>>(Ob, wproj_t, 768, 768, nullptr, nullptr, nullptr, out, b_proj);
}

// Round 2
// 118.968 us; speedup vs baseline: 1.5281x; 1.5281x over previous
//
#include <hip/hip_runtime.h>
#include <hip/hip_bf16.h>

typedef __attribute__((ext_vector_type(8))) short short8;
typedef __attribute__((ext_vector_type(4))) float f32x4;

#define HD 64
#define NH 12
#define SEQ 2048
#define CDIM 768

static __device__ __forceinline__ unsigned short f2bf(float f) {
    __hip_bfloat16 h = __float2bfloat16(f);
    return __builtin_bit_cast(unsigned short, h);
}

// ---------------- convert x (f32 -> bf16) ----------------
__global__ void convert_x_kernel(const float* __restrict__ in, unsigned short* __restrict__ out, int n4) {
    int i = blockIdx.x * blockDim.x + threadIdx.x;
    const int stride = gridDim.x * blockDim.x;
    for (; i < n4; i += stride) {
        const float4 v = reinterpret_cast<const float4*>(in)[i];
        ushort4 o;
        o.x = f2bf(v.x); o.y = f2bf(v.y); o.z = f2bf(v.z); o.w = f2bf(v.w);
        reinterpret_cast<ushort4*>(out)[i] = o;
    }
}

// ---------------- transpose + convert (f32 [K][C] -> bf16 [C][K]) ----------------
__global__ __launch_bounds__(256) void transpose_conv_kernel(const float* __restrict__ in,
        unsigned short* __restrict__ out, int K, int C) {
    __shared__ float t[32][33];
    const int k0 = blockIdx.x * 32, c0 = blockIdx.y * 32;
    const int r = threadIdx.x >> 3, c4 = (threadIdx.x & 7) * 4;
    const float4 v = *reinterpret_cast<const float4*>(in + (size_t)(k0 + r) * C + c0 + c4);
    t[r][c4 + 0] = v.x; t[r][c4 + 1] = v.y; t[r][c4 + 2] = v.z; t[r][c4 + 3] = v.w;
    __syncthreads();
    ushort4 o;
    o.x = f2bf(t[c4 + 0][r]); o.y = f2bf(t[c4 + 1][r]);
    o.z = f2bf(t[c4 + 2][r]); o.w = f2bf(t[c4 + 3][r]);
    *reinterpret_cast<ushort4*>(out + (size_t)(c0 + r) * K + k0 + c4) = o;
}

// ---------------- MFMA GEMM: C[M,N] = A[M,K] @ Bt[N,K]^T ----------------
// EPI==0: scatter bf16: Q (pre-scaled by 1/8) & K -> [B*NH][SEQ][HD], V -> TRANSPOSED [B*NH][HD][SEQ]
// EPI==1: fp32 out += bias
template<int EPI>
__global__ __launch_bounds__(256, 2) void gemm_kernel(
    const unsigned short* __restrict__ A,
    const unsigned short* __restrict__ Bt,
    const int K, const int N,
    unsigned short* __restrict__ Qo, unsigned short* __restrict__ Ko, unsigned short* __restrict__ Vo,
    float* __restrict__ Cout, const float* __restrict__ bias)
{
    const int tid = threadIdx.x;
    const int wave = tid >> 6, lane = tid & 63;
    const int g = lane >> 4, li = lane & 15;
    const int wr = wave >> 1, wc = wave & 1;
    const int m0 = blockIdx.x * 128, n0 = blockIdx.y * 128;

    __shared__ short As[128 * 40];
    __shared__ short Bs[128 * 40];

    f32x4 acc[4][4];
    #pragma unroll
    for (int i = 0; i < 4; i++)
        #pragma unroll
        for (int j = 0; j < 4; j++)
            acc[i][j] = (f32x4){0.f, 0.f, 0.f, 0.f};

    const int sr = tid >> 1, sc = (tid & 1) * 16;
    const unsigned short* aSrc = A + (size_t)(m0 + sr) * K + sc;
    const unsigned short* bSrc = Bt + (size_t)(n0 + sr) * K + sc;
    short* aDst = As + sr * 40 + sc;
    short* bDst = Bs + sr * 40 + sc;

    for (int k0 = 0; k0 < K; k0 += 32) {
        __syncthreads();
        *reinterpret_cast<short8*>(aDst)     = *reinterpret_cast<const short8*>(aSrc + k0);
        *reinterpret_cast<short8*>(aDst + 8) = *reinterpret_cast<const short8*>(aSrc + k0 + 8);
        *reinterpret_cast<short8*>(bDst)     = *reinterpret_cast<const short8*>(bSrc + k0);
        *reinterpret_cast<short8*>(bDst + 8) = *reinterpret_cast<const short8*>(bSrc + k0 + 8);
        __syncthreads();
        short8 af[4], bfr[4];
        #pragma unroll
        for (int mf = 0; mf < 4; mf++)
            af[mf] = *reinterpret_cast<const short8*>(As + (wr * 64 + mf * 16 + li) * 40 + 8 * g);
        #pragma unroll
        for (int nf = 0; nf < 4; nf++)
            bfr[nf] = *reinterpret_cast<const short8*>(Bs + (wc * 64 + nf * 16 + li) * 40 + 8 * g);
        #pragma unroll
        for (int mf = 0; mf < 4; mf++)
            #pragma unroll
            for (int nf = 0; nf < 4; nf++)
                acc[mf][nf] = __builtin_amdgcn_mfma_f32_16x16x32_bf16(af[mf], bfr[nf], acc[mf][nf], 0, 0, 0);
    }

    #pragma unroll
    for (int mf = 0; mf < 4; mf++) {
        #pragma unroll
        for (int nf = 0; nf < 4; nf++) {
            #pragma unroll
            for (int j = 0; j < 4; j++) {
                const int r = m0 + wr * 64 + mf * 16 + 4 * g + j;
                const int c = n0 + wc * 64 + nf * 16 + li;
                const float v = acc[mf][nf][j];
                if (EPI == 0) {
                    const int s = c / 768, rem = c % 768;
                    const int hh = rem >> 6, d = rem & 63;
                    const int bb = r >> 11, n = r & (SEQ - 1);
                    if (s == 0)
                        Qo[(((size_t)bb * NH + hh) * SEQ + n) * HD + d] = f2bf(v * 0.125f);
                    else if (s == 1)
                        Ko[(((size_t)bb * NH + hh) * SEQ + n) * HD + d] = f2bf(v);
                    else
                        Vo[(((size_t)bb * NH + hh) * HD + d) * SEQ + n] = f2bf(v);
                } else {
                    Cout[(size_t)r * N + c] = v + bias[c];
                }
            }
        }
    }
}

// ---------------- flash attention (swapped-operand, in-register softmax) ----------------
// Q: bf16 [B*NH][SEQ][HD] pre-scaled by 1/8; Kg: bf16 [B*NH][SEQ][HD];
// Vtg: bf16 [B*NH][HD][SEQ] (transposed); O: bf16 [B][SEQ][CDIM]
//
// QK^T computed swapped: mfma(A=K-rows, B=Q-rows) -> lane (g,li) holds
// S[q=li][i = 16*kt + 4*g + j] for kt=0..3, j=0..3 (16 scores per lane, one q-row).
// K rows are staged PERMUTED: staged row i <- global row kv0 + kappa(i),
// kappa(i) = 32*(kt&1) + 8*g + 4*(kt>>1) + j. Softmax is permutation-invariant,
// and this kappa makes the post-softmax registers form EXACTLY the PV B-fragment
// (slot kappa_pos = 32*h + 8*g + s maps to p[h + 2*(s>>2)][s&3]) with zero
// cross-lane data movement. V^T is staged naturally so column c = key kv0+c.
__global__ __launch_bounds__(256, 2) void attn_kernel(
    const unsigned short* __restrict__ Q,
    const unsigned short* __restrict__ Kg,
    const unsigned short* __restrict__ Vtg,
    unsigned short* __restrict__ O)
{
    const int tid = threadIdx.x;
    const int wave = tid >> 6, lane = tid & 63;
    const int g = lane >> 4, li = lane & 15;
    const int head = blockIdx.y;
    const int b = head / NH, h = head % NH;
    const int q0 = blockIdx.x * 64 + wave * 16;
    const size_t plane = (size_t)head * SEQ * HD;

    __shared__ short Ks[64 * 72];
    __shared__ short Vs[64 * 72];

    short8 qf0, qf1;
    {
        const unsigned short* qp = Q + plane + (size_t)(q0 + li) * HD + 8 * g;
        qf0 = *reinterpret_cast<const short8*>(qp);
        qf1 = *reinterpret_cast<const short8*>(qp + 32);
    }

    float m_run = -1e30f, l_run = 0.f;
    f32x4 o_acc[4];
    #pragma unroll
    for (int nf = 0; nf < 4; nf++) o_acc[nf] = (f32x4){0.f, 0.f, 0.f, 0.f};

    // staging: thread covers LDS row sr, 16 shorts at col sc
    const int sr = tid >> 2, sc = (tid & 3) * 16;
    const int kt_s = sr >> 4, g_s = (sr >> 2) & 3, j_s = sr & 3;
    const int kperm = 32 * (kt_s & 1) + 8 * g_s + 4 * (kt_s >> 1) + j_s;
    const unsigned short* ksrc0 = Kg + plane + (size_t)kperm * HD + sc;
    const unsigned short* vsrc0 = Vtg + plane + (size_t)sr * SEQ + sc;
    short* kdst = Ks + sr * 72 + sc;
    short* vdst = Vs + sr * 72 + sc;

    for (int kv0 = 0; kv0 < SEQ; kv0 += 64) {
        __syncthreads();
        *reinterpret_cast<short8*>(kdst)     = *reinterpret_cast<const short8*>(ksrc0 + (size_t)kv0 * HD);
        *reinterpret_cast<short8*>(kdst + 8) = *reinterpret_cast<const short8*>(ksrc0 + (size_t)kv0 * HD + 8);
        *reinterpret_cast<short8*>(vdst)     = *reinterpret_cast<const short8*>(vsrc0 + kv0);
        *reinterpret_cast<short8*>(vdst + 8) = *reinterpret_cast<const short8*>(vsrc0 + kv0 + 8);
        __syncthreads();

        // QK^T (swapped)
        f32x4 s_acc[4];
        #pragma unroll
        for (int kt = 0; kt < 4; kt++) s_acc[kt] = (f32x4){0.f, 0.f, 0.f, 0.f};
        __builtin_amdgcn_s_setprio(1);
        #pragma unroll
        for (int kt = 0; kt < 4; kt++) {
            const short8 ka0 = *reinterpret_cast<const short8*>(&Ks[(16 * kt + li) * 72 + 8 * g]);
            const short8 ka1 = *reinterpret_cast<const short8*>(&Ks[(16 * kt + li) * 72 + 8 * g + 32]);
            s_acc[kt] = __builtin_amdgcn_mfma_f32_16x16x32_bf16(ka0, qf0, s_acc[kt], 0, 0, 0);
            s_acc[kt] = __builtin_amdgcn_mfma_f32_16x16x32_bf16(ka1, qf1, s_acc[kt], 0, 0, 0);
        }
        __builtin_amdgcn_s_setprio(0);

        // in-register row max (+2 shuffles)
        float t01 = fmaxf(fmaxf(s_acc[0][0], s_acc[0][1]), fmaxf(s_acc[0][2], s_acc[0][3]));
        float t11 = fmaxf(fmaxf(s_acc[1][0], s_acc[1][1]), fmaxf(s_acc[1][2], s_acc[1][3]));
        float t21 = fmaxf(fmaxf(s_acc[2][0], s_acc[2][1]), fmaxf(s_acc[2][2], s_acc[2][3]));
        float t31 = fmaxf(fmaxf(s_acc[3][0], s_acc[3][1]), fmaxf(s_acc[3][2], s_acc[3][3]));
        float t = fmaxf(fmaxf(t01, t11), fmaxf(t21, t31));
        t = fmaxf(t, __shfl_xor(t, 16));
        t = fmaxf(t, __shfl_xor(t, 32));

        // defer-max: only rescale when max grew by >8 (T13)
        if (!__all(t <= m_run + 8.0f)) {
            const float mnew = fmaxf(m_run, t);
            const float corr = __expf(m_run - mnew);
            m_run = mnew;
            l_run *= corr;
            #pragma unroll
            for (int nf = 0; nf < 4; nf++)
                #pragma unroll
                for (int j = 0; j < 4; j++) o_acc[nf][j] *= corr;
        }

        float p[4][4];
        float sum = 0.f;
        #pragma unroll
        for (int kt = 0; kt < 4; kt++)
            #pragma unroll
            for (int j = 0; j < 4; j++) {
                p[kt][j] = __expf(s_acc[kt][j] - m_run);
                sum += p[kt][j];
            }
        sum += __shfl_xor(sum, 16);
        sum += __shfl_xor(sum, 32);
        l_run += sum;

        // pack PV B-fragment directly from registers (kperm makes layout exact)
        short8 pa0, pa1;
        #pragma unroll
        for (int s = 0; s < 4; s++) {
            pa0[s]     = (short)f2bf(p[0][s]);
            pa0[s + 4] = (short)f2bf(p[2][s]);
            pa1[s]     = (short)f2bf(p[1][s]);
            pa1[s + 4] = (short)f2bf(p[3][s]);
        }

        // PV (swapped): o_acc[nf] holds O[q=li][d = 16*nf + 4*g + j]
        __builtin_amdgcn_s_setprio(1);
        #pragma unroll
        for (int nf = 0; nf < 4; nf++) {
            const short8 va0 = *reinterpret_cast<const short8*>(&Vs[(16 * nf + li) * 72 + 8 * g]);
            const short8 va1 = *reinterpret_cast<const short8*>(&Vs[(16 * nf + li) * 72 + 8 * g + 32]);
            o_acc[nf] = __builtin_amdgcn_mfma_f32_16x16x32_bf16(va0, pa0, o_acc[nf], 0, 0, 0);
            o_acc[nf] = __builtin_amdgcn_mfma_f32_16x16x32_bf16(va1, pa1, o_acc[nf], 0, 0, 0);
        }
        __builtin_amdgcn_s_setprio(0);
    }

    const float inv = 1.0f / l_run;
    unsigned short* dst = O + ((size_t)b * SEQ + q0 + li) * CDIM + h * HD + 4 * g;
    #pragma unroll
    for (int nf = 0; nf < 4; nf++) {
        ushort4 o;
        o.x = f2bf(o_acc[nf][0] * inv);
        o.y = f2bf(o_acc[nf][1] * inv);
        o.z = f2bf(o_acc[nf][2] * inv);
        o.w = f2bf(o_acc[nf][3] * inv);
        *reinterpret_cast<ushort4*>(dst + 16 * nf) = o;
    }
}

extern "C" void kernel_launch(void* const* d_in, const int* in_sizes, int n_in,
                              void* d_out, int out_size, void* d_ws, size_t ws_size,
                              hipStream_t stream) {
    const float* x      = (const float*)d_in[0];
    const float* w_qkv  = (const float*)d_in[1];
    const float* w_proj = (const float*)d_in[2];
    const float* b_proj = (const float*)d_in[3];
    float* out = (float*)d_out;

    char* p = (char*)d_ws;
    auto take = [&](size_t bytes) { char* r = p; p += (bytes + 255) & ~(size_t)255; return r; };
    unsigned short* xb      = (unsigned short*)take((size_t)4096 * 768 * 2);
    unsigned short* wqkv_t  = (unsigned short*)take((size_t)2304 * 768 * 2);
    unsigned short* wproj_t = (unsigned short*)take((size_t)768 * 768 * 2);
    unsigned short* Qb      = (unsigned short*)take((size_t)24 * 2048 * 64 * 2);
    unsigned short* Kb      = (unsigned short*)take((size_t)24 * 2048 * 64 * 2);
    unsigned short* Vb      = (unsigned short*)take((size_t)24 * 2048 * 64 * 2);  // [B*NH][HD][SEQ]
    unsigned short* Ob      = (unsigned short*)take((size_t)4096 * 768 * 2);

    convert_x_kernel<<<1024, 256, 0, stream>>>(x, xb, 4096 * 768 / 4);
    transpose_conv_kernel<<<dim3(24, 72), 256, 0, stream>>>(w_qkv, wqkv_t, 768, 2304);
    transpose_conv_kernel<<<dim3(24, 24), 256, 0, stream>>>(w_proj, wproj_t, 768, 768);
    gemm_kernel<0><<<dim3(32, 18), 256, 0, stream>>>(xb, wqkv_t, 768, 2304, Qb, Kb, Vb, nullptr, nullptr);
    attn_kernel<<<dim3(32, 24), 256, 0, stream>>>(Qb, Kb, Vb, Ob);
    gemm_kernel<1><<<dim3(32, 6), 256, 0, stream>>>(Ob, wproj_t, 768, 768, nullptr, nullptr, nullptr, out, b_proj);
}

// Round 3
// 114.178 us; speedup vs baseline: 1.5922x; 1.0420x over previous
//
#include <hip/hip_runtime.h>
#include <hip/hip_bf16.h>

typedef __attribute__((ext_vector_type(8))) short short8;
typedef __attribute__((ext_vector_type(4))) float f32x4;

#define HD 64
#define NH 12
#define SEQ 2048
#define CDIM 768

// Q is pre-scaled by (1/sqrt(64)) * log2(e) so softmax runs in exp2 domain.
#define QSCALE 0.180336880f
#define LOG2_THR 11.5f

static __device__ __forceinline__ unsigned short f2bf(float f) {
    __hip_bfloat16 h = __float2bfloat16(f);
    return __builtin_bit_cast(unsigned short, h);
}

#define GLDS16(gp, lp) __builtin_amdgcn_global_load_lds( \
    (const __attribute__((address_space(1))) void*)(gp), \
    (__attribute__((address_space(3))) void*)(lp), 16, 0, 0)

// ---------------- fused prep: transpose+convert both weights, convert x ----------------
static __device__ __forceinline__ void transpose_tile(const float* __restrict__ in,
        unsigned short* __restrict__ out, int K, int C, int bx, int by,
        float (*t)[33], int tid) {
    const int k0 = bx * 32, c0 = by * 32;
    const int r = tid >> 3, c4 = (tid & 7) * 4;
    const float4 v = *reinterpret_cast<const float4*>(in + (size_t)(k0 + r) * C + c0 + c4);
    t[r][c4 + 0] = v.x; t[r][c4 + 1] = v.y; t[r][c4 + 2] = v.z; t[r][c4 + 3] = v.w;
    __syncthreads();
    ushort4 o;
    o.x = f2bf(t[c4 + 0][r]); o.y = f2bf(t[c4 + 1][r]);
    o.z = f2bf(t[c4 + 2][r]); o.w = f2bf(t[c4 + 3][r]);
    *reinterpret_cast<ushort4*>(out + (size_t)(c0 + r) * K + k0 + c4) = o;
}

__global__ __launch_bounds__(256) void prep_kernel(
        const float* __restrict__ x, const float* __restrict__ wq, const float* __restrict__ wp,
        unsigned short* __restrict__ xb, unsigned short* __restrict__ wqt, unsigned short* __restrict__ wpt) {
    __shared__ float t[32][33];
    const int blk = blockIdx.x, tid = threadIdx.x;
    if (blk < 1728) {                       // w_qkv: [768][2304] -> [2304][768]
        transpose_tile(wq, wqt, 768, 2304, blk % 24, blk / 24, t, tid);
    } else if (blk < 2304) {                // w_proj: [768][768] -> [768][768]^T
        const int b2 = blk - 1728;
        transpose_tile(wp, wpt, 768, 768, b2 % 24, b2 / 24, t, tid);
    } else {                                // x: f32 -> bf16 (4 float4 per thread)
        const int b3 = blk - 2304;
        #pragma unroll
        for (int it = 0; it < 4; it++) {
            const int i = (b3 * 4 + it) * 256 + tid;
            const float4 v = reinterpret_cast<const float4*>(x)[i];
            ushort4 o;
            o.x = f2bf(v.x); o.y = f2bf(v.y); o.z = f2bf(v.z); o.w = f2bf(v.w);
            reinterpret_cast<ushort4*>(xb)[i] = o;
        }
    }
}

// ---------------- MFMA GEMM (m97 structure): C[M,N] = A[M,K] @ Bt[N,K]^T ----------------
// LDS [128][32] linear (global_load_lds requires wave-uniform base + lane*16B dest).
// EPI==0: scatter bf16: Q (pre-scaled QSCALE) & K -> [B*NH][SEQ][HD], V -> [B*NH][HD][SEQ]
// EPI==1: fp32 out += bias
template<int EPI>
__global__ __launch_bounds__(256, 2) void gemm_kernel(
    const unsigned short* __restrict__ A,
    const unsigned short* __restrict__ Bt,
    const int K, const int N,
    unsigned short* __restrict__ Qo, unsigned short* __restrict__ Ko, unsigned short* __restrict__ Vo,
    float* __restrict__ Cout, const float* __restrict__ bias)
{
    const int tid = threadIdx.x;
    const int wave = tid >> 6, lane = tid & 63;
    const int g = lane >> 4, li = lane & 15;
    const int wr = wave >> 1, wc = wave & 1;
    const int m0 = blockIdx.x * 128, n0 = blockIdx.y * 128;

    __shared__ short As[128 * 32];
    __shared__ short Bs[128 * 32];

    f32x4 acc[4][4];
    #pragma unroll
    for (int i = 0; i < 4; i++)
        #pragma unroll
        for (int j = 0; j < 4; j++)
            acc[i][j] = (f32x4){0.f, 0.f, 0.f, 0.f};

    // staging: wave w covers rows [w*16, w*16+16) and [w*16+64, w*16+80);
    // lane l -> row w*16 + (l>>2), 16 bytes at col (l&3)*8 shorts. LDS dest is
    // wave-uniform base; HW lands lane l at base + l*16 == row-major [128][32].
    const int srow = wave * 16 + (lane >> 2);
    const int scol = (lane & 3) * 8;
    const unsigned short* aSrc = A + (size_t)(m0 + srow) * K + scol;
    const unsigned short* bSrc = Bt + (size_t)(n0 + srow) * K + scol;
    short* aDst0 = As + wave * 16 * 32;
    short* aDst1 = As + (wave * 16 + 64) * 32;
    short* bDst0 = Bs + wave * 16 * 32;
    short* bDst1 = Bs + (wave * 16 + 64) * 32;
    const size_t rowskip = (size_t)64 * K;

    for (int k0 = 0; k0 < K; k0 += 32) {
        __syncthreads();
        GLDS16(aSrc + k0, aDst0);
        GLDS16(aSrc + k0 + rowskip, aDst1);
        GLDS16(bSrc + k0, bDst0);
        GLDS16(bSrc + k0 + rowskip, bDst1);
        __syncthreads();
        short8 af[4], bfr[4];
        #pragma unroll
        for (int mf = 0; mf < 4; mf++)
            af[mf] = *reinterpret_cast<const short8*>(As + (wr * 64 + mf * 16 + li) * 32 + 8 * g);
        #pragma unroll
        for (int nf = 0; nf < 4; nf++)
            bfr[nf] = *reinterpret_cast<const short8*>(Bs + (wc * 64 + nf * 16 + li) * 32 + 8 * g);
        __builtin_amdgcn_s_setprio(1);
        #pragma unroll
        for (int mf = 0; mf < 4; mf++)
            #pragma unroll
            for (int nf = 0; nf < 4; nf++)
                acc[mf][nf] = __builtin_amdgcn_mfma_f32_16x16x32_bf16(af[mf], bfr[nf], acc[mf][nf], 0, 0, 0);
        __builtin_amdgcn_s_setprio(0);
    }

    #pragma unroll
    for (int mf = 0; mf < 4; mf++) {
        #pragma unroll
        for (int nf = 0; nf < 4; nf++) {
            #pragma unroll
            for (int j = 0; j < 4; j++) {
                const int r = m0 + wr * 64 + mf * 16 + 4 * g + j;
                const int c = n0 + wc * 64 + nf * 16 + li;
                const float v = acc[mf][nf][j];
                if (EPI == 0) {
                    const int s = c / 768, rem = c % 768;
                    const int hh = rem >> 6, d = rem & 63;
                    const int bb = r >> 11, n = r & (SEQ - 1);
                    if (s == 0)
                        Qo[(((size_t)bb * NH + hh) * SEQ + n) * HD + d] = f2bf(v * QSCALE);
                    else if (s == 1)
                        Ko[(((size_t)bb * NH + hh) * SEQ + n) * HD + d] = f2bf(v);
                    else
                        Vo[(((size_t)bb * NH + hh) * HD + d) * SEQ + n] = f2bf(v);
                } else {
                    Cout[(size_t)r * N + c] = v + bias[c];
                }
            }
        }
    }
}

// ---------------- flash attention (swapped-operand, in-reg softmax, async-stage) --------
// Q: bf16 [B*NH][SEQ][HD] pre-scaled by QSCALE; Kg: [B*NH][SEQ][HD]; Vtg: [B*NH][HD][SEQ];
// O: bf16 [B][SEQ][CDIM].  Staging of tile t+1 is issued into registers during compute
// of tile t; raw s_barrier + manual vmcnt/lgkmcnt keep loads in flight across barriers.
__global__ __launch_bounds__(256, 2) void attn_kernel(
    const unsigned short* __restrict__ Q,
    const unsigned short* __restrict__ Kg,
    const unsigned short* __restrict__ Vtg,
    unsigned short* __restrict__ O)
{
    const int tid = threadIdx.x;
    const int wave = tid >> 6, lane = tid & 63;
    const int g = lane >> 4, li = lane & 15;
    const int head = blockIdx.y;
    const int b = head / NH, h = head % NH;
    const int q0 = blockIdx.x * 64 + wave * 16;
    const size_t plane = (size_t)head * SEQ * HD;

    __shared__ short Ks[64 * 72];
    __shared__ short Vs[64 * 72];

    short8 qf0, qf1;
    {
        const unsigned short* qp = Q + plane + (size_t)(q0 + li) * HD + 8 * g;
        qf0 = *reinterpret_cast<const short8*>(qp);
        qf1 = *reinterpret_cast<const short8*>(qp + 32);
    }

    float m_run = -1e30f, l_run = 0.f;   // log2-domain running max / denom
    f32x4 o_acc[4];
    #pragma unroll
    for (int nf = 0; nf < 4; nf++) o_acc[nf] = (f32x4){0.f, 0.f, 0.f, 0.f};

    // staging: thread covers LDS row sr, 16 shorts at col sc; K rows permuted by kappa
    const int sr = tid >> 2, sc = (tid & 3) * 16;
    const int kt_s = sr >> 4, g_s = (sr >> 2) & 3, j_s = sr & 3;
    const int kperm = 32 * (kt_s & 1) + 8 * g_s + 4 * (kt_s >> 1) + j_s;
    const unsigned short* ksrc0 = Kg + plane + (size_t)kperm * HD + sc;
    const unsigned short* vsrc0 = Vtg + plane + (size_t)sr * SEQ + sc;
    short* kdst = Ks + sr * 72 + sc;
    short* vdst = Vs + sr * 72 + sc;

    // prologue: issue tile-0 loads
    short8 krA = *reinterpret_cast<const short8*>(ksrc0);
    short8 krB = *reinterpret_cast<const short8*>(ksrc0 + 8);
    short8 vrA = *reinterpret_cast<const short8*>(vsrc0);
    short8 vrB = *reinterpret_cast<const short8*>(vsrc0 + 8);

    for (int kv0 = 0; kv0 < SEQ; kv0 += 64) {
        asm volatile("s_waitcnt vmcnt(0)" ::: "memory");   // tile-t regs arrived
        __builtin_amdgcn_s_barrier();                       // all waves done reading LDS (tile t-1)
        *reinterpret_cast<short8*>(kdst)     = krA;
        *reinterpret_cast<short8*>(kdst + 8) = krB;
        *reinterpret_cast<short8*>(vdst)     = vrA;
        *reinterpret_cast<short8*>(vdst + 8) = vrB;
        if (kv0 + 64 < SEQ) {                               // issue tile t+1 (stays in flight)
            krA = *reinterpret_cast<const short8*>(ksrc0 + (size_t)(kv0 + 64) * HD);
            krB = *reinterpret_cast<const short8*>(ksrc0 + (size_t)(kv0 + 64) * HD + 8);
            vrA = *reinterpret_cast<const short8*>(vsrc0 + kv0 + 64);
            vrB = *reinterpret_cast<const short8*>(vsrc0 + kv0 + 64 + 8);
        }
        asm volatile("s_waitcnt lgkmcnt(0)" ::: "memory");  // own ds_writes committed
        __builtin_amdgcn_s_barrier();                       // tile t visible to all waves

        // QK^T (swapped): lane holds S2[q=li][16 scores], already in log2 scale
        f32x4 s_acc[4];
        #pragma unroll
        for (int kt = 0; kt < 4; kt++) s_acc[kt] = (f32x4){0.f, 0.f, 0.f, 0.f};
        __builtin_amdgcn_s_setprio(1);
        #pragma unroll
        for (int kt = 0; kt < 4; kt++) {
            const short8 ka0 = *reinterpret_cast<const short8*>(&Ks[(16 * kt + li) * 72 + 8 * g]);
            const short8 ka1 = *reinterpret_cast<const short8*>(&Ks[(16 * kt + li) * 72 + 8 * g + 32]);
            s_acc[kt] = __builtin_amdgcn_mfma_f32_16x16x32_bf16(ka0, qf0, s_acc[kt], 0, 0, 0);
            s_acc[kt] = __builtin_amdgcn_mfma_f32_16x16x32_bf16(ka1, qf1, s_acc[kt], 0, 0, 0);
        }
        __builtin_amdgcn_s_setprio(0);

        float t01 = fmaxf(fmaxf(s_acc[0][0], s_acc[0][1]), fmaxf(s_acc[0][2], s_acc[0][3]));
        float t11 = fmaxf(fmaxf(s_acc[1][0], s_acc[1][1]), fmaxf(s_acc[1][2], s_acc[1][3]));
        float t21 = fmaxf(fmaxf(s_acc[2][0], s_acc[2][1]), fmaxf(s_acc[2][2], s_acc[2][3]));
        float t31 = fmaxf(fmaxf(s_acc[3][0], s_acc[3][1]), fmaxf(s_acc[3][2], s_acc[3][3]));
        float t = fmaxf(fmaxf(t01, t11), fmaxf(t21, t31));
        t = fmaxf(t, __shfl_xor(t, 16));
        t = fmaxf(t, __shfl_xor(t, 32));

        if (!__all(t <= m_run + LOG2_THR)) {                // defer-max (T13)
            const float mnew = fmaxf(m_run, t);
            const float corr = exp2f(m_run - mnew);
            m_run = mnew;
            l_run *= corr;
            #pragma unroll
            for (int nf = 0; nf < 4; nf++)
                #pragma unroll
                for (int j = 0; j < 4; j++) o_acc[nf][j] *= corr;
        }

        float p[4][4];
        float sum = 0.f;
        #pragma unroll
        for (int kt = 0; kt < 4; kt++)
            #pragma unroll
            for (int j = 0; j < 4; j++) {
                p[kt][j] = exp2f(s_acc[kt][j] - m_run);
                sum += p[kt][j];
            }
        sum += __shfl_xor(sum, 16);
        sum += __shfl_xor(sum, 32);
        l_run += sum;

        // pack PV B-fragment directly (kappa permutation makes layout exact)
        short8 pa0, pa1;
        #pragma unroll
        for (int s = 0; s < 4; s++) {
            pa0[s]     = (short)f2bf(p[0][s]);
            pa0[s + 4] = (short)f2bf(p[2][s]);
            pa1[s]     = (short)f2bf(p[1][s]);
            pa1[s + 4] = (short)f2bf(p[3][s]);
        }

        __builtin_amdgcn_s_setprio(1);
        #pragma unroll
        for (int nf = 0; nf < 4; nf++) {
            const short8 va0 = *reinterpret_cast<const short8*>(&Vs[(16 * nf + li) * 72 + 8 * g]);
            const short8 va1 = *reinterpret_cast<const short8*>(&Vs[(16 * nf + li) * 72 + 8 * g + 32]);
            o_acc[nf] = __builtin_amdgcn_mfma_f32_16x16x32_bf16(va0, pa0, o_acc[nf], 0, 0, 0);
            o_acc[nf] = __builtin_amdgcn_mfma_f32_16x16x32_bf16(va1, pa1, o_acc[nf], 0, 0, 0);
        }
        __builtin_amdgcn_s_setprio(0);
    }

    const float inv = 1.0f / l_run;
    unsigned short* dst = O + ((size_t)b * SEQ + q0 + li) * CDIM + h * HD + 4 * g;
    #pragma unroll
    for (int nf = 0; nf < 4; nf++) {
        ushort4 o;
        o.x = f2bf(o_acc[nf][0] * inv);
        o.y = f2bf(o_acc[nf][1] * inv);
        o.z = f2bf(o_acc[nf][2] * inv);
        o.w = f2bf(o_acc[nf][3] * inv);
        *reinterpret_cast<ushort4*>(dst + 16 * nf) = o;
    }
}

extern "C" void kernel_launch(void* const* d_in, const int* in_sizes, int n_in,
                              void* d_out, int out_size, void* d_ws, size_t ws_size,
                              hipStream_t stream) {
    const float* x      = (const float*)d_in[0];
    const float* w_qkv  = (const float*)d_in[1];
    const float* w_proj = (const float*)d_in[2];
    const float* b_proj = (const float*)d_in[3];
    float* out = (float*)d_out;

    char* p = (char*)d_ws;
    auto take = [&](size_t bytes) { char* r = p; p += (bytes + 255) & ~(size_t)255; return r; };
    unsigned short* xb      = (unsigned short*)take((size_t)4096 * 768 * 2);
    unsigned short* wqkv_t  = (unsigned short*)take((size_t)2304 * 768 * 2);
    unsigned short* wproj_t = (unsigned short*)take((size_t)768 * 768 * 2);
    unsigned short* Qb      = (unsigned short*)take((size_t)24 * 2048 * 64 * 2);
    unsigned short* Kb      = (unsigned short*)take((size_t)24 * 2048 * 64 * 2);
    unsigned short* Vb      = (unsigned short*)take((size_t)24 * 2048 * 64 * 2);  // [B*NH][HD][SEQ]
    unsigned short* Ob      = (unsigned short*)take((size_t)4096 * 768 * 2);

    prep_kernel<<<3072, 256, 0, stream>>>(x, w_qkv, w_proj, xb, wqkv_t, wproj_t);
    gemm_kernel<0><<<dim3(32, 18), 256, 0, stream>>>(xb, wqkv_t, 768, 2304, Qb, Kb, Vb, nullptr, nullptr);
    attn_kernel<<<dim3(32, 24), 256, 0, stream>>>(Qb, Kb, Vb, Ob);
    gemm_kernel<1><<<dim3(32, 6), 256, 0, stream>>>(Ob, wproj_t, 768, 768, nullptr, nullptr, nullptr, out, b_proj);
}